// Round 2
// baseline (297.831 us; speedup 1.0000x reference)
//
#include <hip/hip_runtime.h>

#define NTHREADS 256
#define YROWS 40   // y rows staged per 64-row output tile: raw [2*i0-4, 2*i0+35]
#define ICOLS 40   // input cols staged per 64-col output tile
#define TILE_C 64

__device__ __forceinline__ int reflect128(int p) {
    // half-sample symmetric reflection into [0,128); overhang <= 8 so one bounce is enough
    p = (p < 0) ? (-p - 1) : p;
    p = (p >= 128) ? (255 - p) : p;
    return p;
}

// W0[j][k]: coeffs applied to the G0-pair source (Yl or lh), parity (j&1)
// W1[j][k]: coeffs applied to the G1-pair source (hl or hh), parity (j&1)^1
__device__ __forceinline__ void load_w(int j, float* w0, float* w1) {
    const float A =  0.0351638365171441f;
    const float B = -0.0883294244510729f;
    const float C =  0.233890320607236f;
    const float D =  0.760272369066126f;
    const float E =  0.587518297723561f;
    const float F = -0.114301837144249f;
    if (j == 0) {
        w0[0]=0.f; w0[1]=0.f; w0[2]=D;  w0[3]=B;  w0[4]=A;
        w1[0]=0.f; w1[1]=C;   w1[2]=E;  w1[3]=F;  w1[4]=0.f;
    } else if (j == 1) {
        w0[0]=0.f; w0[1]=C;   w0[2]=E;  w0[3]=F;  w0[4]=0.f;
        w1[0]=0.f; w1[1]=0.f; w1[2]=-D; w1[3]=-B; w1[4]=-A;
    } else if (j == 2) {
        w0[0]=0.f; w0[1]=F;   w0[2]=E;  w0[3]=C;  w0[4]=0.f;
        w1[0]=-A;  w1[1]=-B;  w1[2]=-D; w1[3]=0.f; w1[4]=0.f;
    } else {
        w0[0]=A;   w0[1]=B;   w0[2]=D;  w0[3]=0.f; w0[4]=0.f;
        w1[0]=0.f; w1[1]=F;   w1[2]=E;  w1[3]=C;  w1[4]=0.f;
    }
}

__global__ __launch_bounds__(NTHREADS)
void dtcwt_inv_kernel(const float* __restrict__ Yl,
                      const float* __restrict__ Yhr,
                      const float* __restrict__ Yhi,
                      float* __restrict__ out)
{
    const int tid   = threadIdx.x;
    const int ct    = blockIdx.x;   // col tile 0..3
    const int rt    = blockIdx.y;   // row tile 0..3
    const int plane = blockIdx.z;   // 0..511  (b*64+c)

    const int OR0 = rt * 64;
    const int OC0 = ct * 64;
    const int i0r = OR0 >> 2;
    const int i0c = OC0 >> 2;
    const int yrb = 2 * i0r - 4;   // raw first y row staged
    const int icb = 2 * i0c - 4;   // raw first input col staged

    const float* yl = Yl + (size_t)plane * (128 * 128);
    const size_t sb = (size_t)plane * 6 * 4096;   // subband base (64x64 each)

    __shared__ float sYl[YROWS][ICOLS];
    __shared__ float sLh[YROWS][ICOLS];
    __shared__ float sHl[YROWS][ICOLS];
    __shared__ float sHh[YROWS][ICOLS];
    __shared__ float sY1[YROWS][TILE_C];
    __shared__ float sY2[YROWS][TILE_C];

    // ---- Stage Yl window + c2q(lh/hl/hh) windows into LDS ----
    const float RS2 = 0.70710678118654752440f;  // 1/sqrt(2)
    for (int e = tid; e < YROWS * ICOLS; e += NTHREADS) {
        const int t = e / ICOLS;
        const int u = e - t * ICOLS;
        const int ry = reflect128(yrb + t);
        const int ic = reflect128(icb + u);
        sYl[t][u] = yl[ry * 128 + ic];

        const int p = ry & 1, q = ic & 1;
        const int off = (ry >> 1) * 64 + (ic >> 1);
        // c2q: (0,0)->w1r+w2r ; (0,1)->w1i+w2i ; (1,0)->w1i-w2i ; (1,1)->w2r-w1r
        const float* src = (p == q) ? (Yhr + sb) : (Yhi + sb);
        const float sA = (p == 1 && q == 1) ? -RS2 : RS2;
        const float sB = (p == 1 && q == 0) ? -RS2 : RS2;
        // lh: bands (0,5) ; hl: (2,3) ; hh: (1,4)
        float a0 = src[0 * 4096 + off], b0 = src[5 * 4096 + off];
        float a1 = src[2 * 4096 + off], b1 = src[3 * 4096 + off];
        float a2 = src[1 * 4096 + off], b2 = src[4 * 4096 + off];
        sLh[t][u] = sA * a0 + sB * b0;
        sHl[t][u] = sA * a1 + sB * b1;
        sHh[t][u] = sA * a2 + sB * b2;
    }
    __syncthreads();

    // ---- Row filter: build y1,y2 tiles (40 rows x 64 cols) ----
    const int c  = tid & 63;
    const int jc = c & 3;
    float w0c[5], w1c[5];
    load_w(jc, w0c, w1c);
    const int base0 = 2 * (c >> 2) + (jc & 1);         // G0-pair sample parity
    const int base1 = 2 * (c >> 2) + ((jc & 1) ^ 1);   // G1-pair sample parity

    for (int t = tid >> 6; t < YROWS; t += 4) {
        float acc1 = 0.f, acc2 = 0.f;
#pragma unroll
        for (int k = 0; k < 5; ++k) {
            acc1 += sYl[t][base0 + 2 * k] * w0c[k];
            acc1 += sHl[t][base1 + 2 * k] * w1c[k];
            acc2 += sLh[t][base0 + 2 * k] * w0c[k];
            acc2 += sHh[t][base1 + 2 * k] * w1c[k];
        }
        sY1[t][c] = acc1;
        sY2[t][c] = acc2;
    }
    __syncthreads();

    // ---- Column filter: each thread writes 16 output pixels ----
    const int j = tid >> 6;          // output row phase, uniform per wave
    float w0o[5], w1o[5];
    load_w(j, w0o, w1o);
    const int p0 = j & 1;
    const int p1 = p0 ^ 1;

#pragma unroll
    for (int m = 0; m < 16; ++m) {
        float acc = 0.f;
#pragma unroll
        for (int k = 0; k < 5; ++k) {
            acc += sY1[2 * m + p0 + 2 * k][c] * w0o[k];
            acc += sY2[2 * m + p1 + 2 * k][c] * w1o[k];
        }
        const int orow = OR0 + 4 * m + j;
        out[((size_t)plane * 256 + orow) * 256 + OC0 + c] = acc;
    }
}

extern "C" void kernel_launch(void* const* d_in, const int* in_sizes, int n_in,
                              void* d_out, int out_size, void* d_ws, size_t ws_size,
                              hipStream_t stream) {
    const float* Yl  = (const float*)d_in[0];
    const float* Yhr = (const float*)d_in[1];
    const float* Yhi = (const float*)d_in[2];
    float* out = (float*)d_out;

    const int planes = in_sizes[0] / (128 * 128);   // B*C = 512
    dim3 grid(4, 4, planes);
    dtcwt_inv_kernel<<<grid, NTHREADS, 0, stream>>>(Yl, Yhr, Yhi, out);
}

// Round 3
// 276.784 us; speedup vs baseline: 1.0760x; 1.0760x over previous
//
#include <hip/hip_runtime.h>
#include <hip/hip_bf16.h>

#define NTHREADS 256

__device__ __forceinline__ int reflect128(int p) {
    p = (p < 0) ? (-p - 1) : p;
    p = (p >= 128) ? (255 - p) : p;
    return p;
}
__device__ __forceinline__ int reflect64(int p) {
    p = (p < 0) ? (-p - 1) : p;
    p = (p >= 64) ? (127 - p) : p;
    return p;
}

// Filter bank: per phase j, each 5-tap row has exactly 3 consecutive nonzero taps.
// w0 (G0-pair source): start s0[j], coeffs c0[j][0..2]
// w1 (G1-pair source): start s1[j], coeffs c1[j][0..2]
__constant__ int   cs0[4] = {2, 1, 1, 0};
__constant__ int   cs1[4] = {1, 2, 0, 1};
__constant__ float cc0[4][3] = {
    { 0.760272369066126f, -0.0883294244510729f,  0.0351638365171441f},   // D B A
    { 0.233890320607236f,  0.587518297723561f,  -0.114301837144249f},    // C E F
    {-0.114301837144249f,  0.587518297723561f,   0.233890320607236f},    // F E C
    { 0.0351638365171441f, -0.0883294244510729f, 0.760272369066126f}};   // A B D
__constant__ float cc1[4][3] = {
    { 0.233890320607236f,  0.587518297723561f,  -0.114301837144249f},    // C E F
    {-0.760272369066126f,  0.0883294244510729f, -0.0351638365171441f},   // -D -B -A
    {-0.0351638365171441f, 0.0883294244510729f, -0.760272369066126f},    // -A -B -D
    {-0.114301837144249f,  0.587518297723561f,   0.233890320607236f}};   // F E C

__global__ __launch_bounds__(NTHREADS, 4)
void dtcwt_inv_kernel(const float* __restrict__ Yl,
                      const float* __restrict__ Yhr,
                      const float* __restrict__ Yhi,
                      float* __restrict__ out)
{
    const int tid   = threadIdx.x;
    const int ct    = blockIdx.x;   // col tile 0..3
    const int rt    = blockIdx.y;   // row tile 0..3
    const int plane = blockIdx.z;   // 0..511

    const int OR0 = rt * 64, OC0 = ct * 64;
    const int i0r = OR0 >> 2, i0c = OC0 >> 2;
    const int yrb = 2 * i0r - 4;    // raw first y row staged (even)
    const int icb = 2 * i0c - 4;    // raw first input col staged (even)

    const float* yl = Yl + (size_t)plane * (128 * 128);
    const float* hr = Yhr + (size_t)plane * 6 * 4096;
    const float* hi = Yhi + (size_t)plane * 6 * 4096;

    // parity-split staging: [col parity][row t][half-col h]
    __shared__ float sYl[2][40][20];
    __shared__ float sLh[2][40][20];
    __shared__ float sHl[2][40][20];
    __shared__ float sHh[2][40][20];
    // row-filter output, parity-split by row, bf16: [row parity][half-row g][col c]
    __shared__ __hip_bfloat16 sY1[2][20][64];
    __shared__ __hip_bfloat16 sY2[2][20][64];

    const float RS2 = 0.70710678118654752440f;  // 1/sqrt(2)

    // ---- Phase A1: stage Yl window (40x40, reflected), parity-split by col ----
    for (int e = tid; e < 1600; e += NTHREADS) {
        const int t = e / 40;
        const int u = e - t * 40;
        const int ry = reflect128(yrb + t);
        const int ic = reflect128(icb + u);
        sYl[u & 1][t][u >> 1] = yl[ry * 128 + ic];
    }

    // ---- Phase A2: c2q per 2x2 quad (12 loads -> 12 staged values) ----
    for (int e = tid; e < 400; e += NTHREADS) {
        const int t2 = e / 20;
        const int u2 = e - t2 * 20;
        const int r2 = reflect64(i0r - 2 + t2);
        const int c2 = reflect64(i0c - 2 + u2);
        const int off = r2 * 64 + c2;
        float ar0 = hr[0 * 4096 + off], ar1 = hr[1 * 4096 + off], ar2 = hr[2 * 4096 + off];
        float ar3 = hr[3 * 4096 + off], ar4 = hr[4 * 4096 + off], ar5 = hr[5 * 4096 + off];
        float ai0 = hi[0 * 4096 + off], ai1 = hi[1 * 4096 + off], ai2 = hi[2 * 4096 + off];
        float ai3 = hi[3 * 4096 + off], ai4 = hi[4 * 4096 + off], ai5 = hi[5 * 4096 + off];
#pragma unroll
        for (int dt = 0; dt < 2; ++dt) {
#pragma unroll
            for (int du = 0; du < 2; ++du) {
                const int t = 2 * t2 + dt, u = 2 * u2 + du;
                const int p = reflect128(yrb + t) & 1;
                const int q = reflect128(icb + u) & 1;
                const float sA = (p & q) ? -RS2 : RS2;
                const float sB = (p & ~q & 1) ? -RS2 : RS2;
                float b0, b5, b2v, b3, b1, b4;
                if (p == q) { b0 = ar0; b5 = ar5; b2v = ar2; b3 = ar3; b1 = ar1; b4 = ar4; }
                else        { b0 = ai0; b5 = ai5; b2v = ai2; b3 = ai3; b1 = ai1; b4 = ai4; }
                sLh[du][t][u2] = sA * b0 + sB * b5;
                sHl[du][t][u2] = sA * b2v + sB * b3;
                sHh[du][t][u2] = sA * b1 + sB * b4;
            }
        }
    }
    __syncthreads();

    // ---- Phase B: row filter -> y1,y2 (40 rows x 64 cols), bf16 into LDS ----
    const int c  = tid & 63;
    const int jc = c & 3;
    const int pc0 = jc & 1;          // col parity of G0-pair taps
    const int pc1 = pc0 ^ 1;         // col parity of G1-pair taps
    const int h0 = (c >> 2) + cs0[jc];
    const int h1 = (c >> 2) + cs1[jc];
    const float a0 = cc0[jc][0], a1 = cc0[jc][1], a2 = cc0[jc][2];
    const float b0w = cc1[jc][0], b1w = cc1[jc][1], b2w = cc1[jc][2];

    for (int t = tid >> 6; t < 40; t += 4) {
        const float* yl0 = &sYl[pc0][t][h0];
        const float* hl1 = &sHl[pc1][t][h1];
        const float* lh0 = &sLh[pc0][t][h0];
        const float* hh1 = &sHh[pc1][t][h1];
        float acc1 = yl0[0] * a0 + yl0[1] * a1 + yl0[2] * a2
                   + hl1[0] * b0w + hl1[1] * b1w + hl1[2] * b2w;
        float acc2 = lh0[0] * a0 + lh0[1] * a1 + lh0[2] * a2
                   + hh1[0] * b0w + hh1[1] * b1w + hh1[2] * b2w;
        sY1[t & 1][t >> 1][c] = __float2bfloat16(acc1);
        sY2[t & 1][t >> 1][c] = __float2bfloat16(acc2);
    }
    __syncthreads();

    // ---- Phase C: column filter, each thread -> 16 output pixels ----
    const int j  = tid >> 6;         // output row phase (wave-uniform)
    const int p0 = j & 1, p1 = p0 ^ 1;
    const int g0 = cs0[j], g1 = cs1[j];
    const float d0 = cc0[j][0], d1 = cc0[j][1], d2 = cc0[j][2];
    const float e0 = cc1[j][0], e1 = cc1[j][1], e2 = cc1[j][2];

    float* orow = out + ((size_t)plane * 256 + OR0 + j) * 256 + OC0 + c;
#pragma unroll
    for (int m = 0; m < 16; ++m) {
        float acc = __bfloat162float(sY1[p0][m + g0][c]) * d0
                  + __bfloat162float(sY1[p0][m + g0 + 1][c]) * d1
                  + __bfloat162float(sY1[p0][m + g0 + 2][c]) * d2
                  + __bfloat162float(sY2[p1][m + g1][c]) * e0
                  + __bfloat162float(sY2[p1][m + g1 + 1][c]) * e1
                  + __bfloat162float(sY2[p1][m + g1 + 2][c]) * e2;
        orow[(size_t)(4 * m) * 256] = acc;
    }
}

extern "C" void kernel_launch(void* const* d_in, const int* in_sizes, int n_in,
                              void* d_out, int out_size, void* d_ws, size_t ws_size,
                              hipStream_t stream) {
    const float* Yl  = (const float*)d_in[0];
    const float* Yhr = (const float*)d_in[1];
    const float* Yhi = (const float*)d_in[2];
    float* out = (float*)d_out;

    const int planes = in_sizes[0] / (128 * 128);   // B*C = 512
    dim3 grid(4, 4, planes);
    dtcwt_inv_kernel<<<grid, NTHREADS, 0, stream>>>(Yl, Yhr, Yhi, out);
}

// Round 4
// 274.907 us; speedup vs baseline: 1.0834x; 1.0068x over previous
//
#include <hip/hip_runtime.h>
#include <hip/hip_bf16.h>

#define NTHREADS 256

__device__ __forceinline__ int reflect128(int p) {
    p = (p < 0) ? (-p - 1) : p;
    p = (p >= 128) ? (255 - p) : p;
    return p;
}

// Per output phase j: 3 consecutive nonzero taps out of 5.
// cc0/cs0 apply to the G0-pair source (Yl or lh), cc1/cs1 to the G1-pair (hl or hh).
__constant__ int   cs0[4] = {2, 1, 1, 0};
__constant__ int   cs1[4] = {1, 2, 0, 1};
__constant__ float cc0[4][3] = {
    { 0.760272369066126f, -0.0883294244510729f,  0.0351638365171441f},
    { 0.233890320607236f,  0.587518297723561f,  -0.114301837144249f},
    {-0.114301837144249f,  0.587518297723561f,   0.233890320607236f},
    { 0.0351638365171441f, -0.0883294244510729f, 0.760272369066126f}};
__constant__ float cc1[4][3] = {
    { 0.233890320607236f,  0.587518297723561f,  -0.114301837144249f},
    {-0.760272369066126f,  0.0883294244510729f, -0.0351638365171441f},
    {-0.0351638365171441f, 0.0883294244510729f, -0.760272369066126f},
    {-0.114301837144249f,  0.587518297723561f,   0.233890320607236f}};

__global__ __launch_bounds__(NTHREADS, 5)
void dtcwt_inv_kernel(const float* __restrict__ Yl,
                      const float* __restrict__ Yhr,
                      const float* __restrict__ Yhi,
                      float* __restrict__ out)
{
    const int tid   = threadIdx.x;
    const int ct    = blockIdx.x;   // col tile 0..3
    const int rt    = blockIdx.y;   // row tile 0..3
    const int plane = blockIdx.z;   // 0..511

    const int OR0 = rt * 64, OC0 = ct * 64;
    const int i0r = OR0 >> 2, i0c = OC0 >> 2;
    const int yrb = 2 * i0r - 4;    // raw first y row of the 40-row window (even)
    const int icb = 2 * i0c - 4;    // raw first input col of the 40-col window (even)

    const float* yl = Yl + (size_t)plane * (128 * 128);
    const float* hr = Yhr + (size_t)plane * 6 * 4096;
    const float* hi = Yhi + (size_t)plane * 6 * 4096;

    // natural-order staging (taps read at stride-2 dwords -> 2-way max = free)
    __shared__ float sLh[40][40];
    __shared__ float sHl[40][40];
    __shared__ float sHh[40][40];
    __shared__ __hip_bfloat16 sY1[40][64];
    __shared__ __hip_bfloat16 sY2[40][64];

    const float RS2 = 0.70710678118654752440f;  // 1/sqrt(2)

    // ---- Phase A: c2q per 2x2 quad; 12 global loads -> 12 staged values ----
    for (int e = tid; e < 400; e += NTHREADS) {
        const int t2 = e / 20;
        const int u2 = e - t2 * 20;
        const int ar = i0r - 2 + t2;
        const int ac = i0c - 2 + u2;
        const int oobr = (ar < 0) | (ar >= 64);
        const int oobc = (ac < 0) | (ac >= 64);
        const int r2 = oobr ? ((ar < 0) ? (-ar - 1) : (127 - ar)) : ar;
        const int c2 = oobc ? ((ac < 0) ? (-ac - 1) : (127 - ac)) : ac;
        const int off = r2 * 64 + c2;
        const float ar0 = hr[off], ar1 = hr[4096 + off], ar2 = hr[2 * 4096 + off];
        const float ar3 = hr[3 * 4096 + off], ar4 = hr[4 * 4096 + off], ar5 = hr[5 * 4096 + off];
        const float ai0 = hi[off], ai1 = hi[4096 + off], ai2 = hi[2 * 4096 + off];
        const float ai3 = hi[3 * 4096 + off], ai4 = hi[4 * 4096 + off], ai5 = hi[5 * 4096 + off];
#pragma unroll
        for (int dt = 0; dt < 2; ++dt) {
#pragma unroll
            for (int du = 0; du < 2; ++du) {
                const int p = dt ^ oobr;            // reflection flips sample parity
                const int q = du ^ oobc;
                const float sA = (p & q) ? -RS2 : RS2;
                const float sB = (p & (q ^ 1)) ? -RS2 : RS2;
                float b0, b5, b2v, b3, b1, b4;
                if (p == q) { b0 = ar0; b5 = ar5; b2v = ar2; b3 = ar3; b1 = ar1; b4 = ar4; }
                else        { b0 = ai0; b5 = ai5; b2v = ai2; b3 = ai3; b1 = ai1; b4 = ai4; }
                const int t = 2 * t2 + dt, u = 2 * u2 + du;
                sLh[t][u] = sA * b0 + sB * b5;
                sHl[t][u] = sA * b2v + sB * b3;
                sHh[t][u] = sA * b1 + sB * b4;
            }
        }
    }
    __syncthreads();

    // ---- Phase B: row filter -> y1,y2 (40 rows x 64 cols), Yl straight from global ----
    const int c  = tid & 63;
    const int jc = c & 3;
    const int q2 = c >> 2;
    const float a0 = cc0[jc][0], a1 = cc0[jc][1], a2 = cc0[jc][2];
    const float b0w = cc1[jc][0], b1w = cc1[jc][1], b2w = cc1[jc][2];
    const int ub0 = 2 * q2 + (jc & 1) + 2 * cs0[jc];          // first G0 tap col (staged u)
    const int ub1 = 2 * q2 + ((jc & 1) ^ 1) + 2 * cs1[jc];    // first G1 tap col
    const int ic0 = reflect128(icb + ub0);                    // reflected global Yl cols
    const int ic1 = reflect128(icb + ub0 + 2);
    const int ic2 = reflect128(icb + ub0 + 4);

    for (int t = tid >> 6; t < 40; t += 4) {
        const int ry = reflect128(yrb + t);
        const float* yrow = yl + ry * 128;
        float acc1 = yrow[ic0] * a0 + yrow[ic1] * a1 + yrow[ic2] * a2
                   + sHl[t][ub1] * b0w + sHl[t][ub1 + 2] * b1w + sHl[t][ub1 + 4] * b2w;
        float acc2 = sLh[t][ub0] * a0 + sLh[t][ub0 + 2] * a1 + sLh[t][ub0 + 4] * a2
                   + sHh[t][ub1] * b0w + sHh[t][ub1 + 2] * b1w + sHh[t][ub1 + 4] * b2w;
        sY1[t][c] = __float2bfloat16(acc1);
        sY2[t][c] = __float2bfloat16(acc2);
    }
    __syncthreads();

    // ---- Phase C: column filter, each thread -> 16 output pixels ----
    const int j  = tid >> 6;                 // wave-uniform output row phase
    const int p0 = j & 1, p1 = p0 ^ 1;
    const int r0 = p0 + 2 * cs0[j];          // y1 tap rows: 2m + r0 + {0,2,4}
    const int r1 = p1 + 2 * cs1[j];
    const float d0 = cc0[j][0], d1 = cc0[j][1], d2 = cc0[j][2];
    const float e0 = cc1[j][0], e1 = cc1[j][1], e2 = cc1[j][2];

    float* op = out + ((size_t)plane * 256 + OR0 + j) * 256 + OC0 + c;
#pragma unroll
    for (int m = 0; m < 16; ++m) {
        float acc = __bfloat162float(sY1[2 * m + r0][c]) * d0
                  + __bfloat162float(sY1[2 * m + r0 + 2][c]) * d1
                  + __bfloat162float(sY1[2 * m + r0 + 4][c]) * d2
                  + __bfloat162float(sY2[2 * m + r1][c]) * e0
                  + __bfloat162float(sY2[2 * m + r1 + 2][c]) * e1
                  + __bfloat162float(sY2[2 * m + r1 + 4][c]) * e2;
        op[(size_t)m * 1024] = acc;
    }
}

extern "C" void kernel_launch(void* const* d_in, const int* in_sizes, int n_in,
                              void* d_out, int out_size, void* d_ws, size_t ws_size,
                              hipStream_t stream) {
    const float* Yl  = (const float*)d_in[0];
    const float* Yhr = (const float*)d_in[1];
    const float* Yhi = (const float*)d_in[2];
    float* out = (float*)d_out;

    const int planes = in_sizes[0] / (128 * 128);   // B*C = 512
    dim3 grid(4, 4, planes);
    dtcwt_inv_kernel<<<grid, NTHREADS, 0, stream>>>(Yl, Yhr, Yhi, out);
}